// Round 14
// baseline (201.697 us; speedup 1.0000x reference)
//
#include <hip/hip_runtime.h>

#define NB   512
#define NN   50
#define LLn  50
#define HD   128
#define OUTN 99999

// ---------------- ws byte offsets ----------------
#define WS_W1T   0         // fp32 [128][128] transposed
#define WS_W2T   65536     // fp32 [128][128] transposed (unused, kept)
#define WS_WTT   131072    // fp32 [256][128] transposed
#define WS_WEH   262144    // bf16 hi [256 n][128 k]
#define WS_WEL   327680
#define WS_WCATH 393216    // bf16 hi [384 n][384 k]
#define WS_WCATL 688128
#define WS_AHI   983040    // a-final hi image [2 kh][512 b][128 B]
#define WS_ALO   1114112
#define WS_W2H   1245184   // bf16 hi [128 n][128 k]
#define WS_W2L   1277952

// ---------------- k1f LDS (78336 B -> 2 blocks/CU, 256 thr = 4 waves) ----------------
#define LDS_HH    0        // [50][256B] bf16 hi swizzled (overrun rows -> HL: M-dim junk ok)
#define LDS_HL    12800
#define LDS_AIH   25600    // A image [64n][64m] hi (one sel at a time)
#define LDS_AIL   33792
#define LDS_HETH  41984    // he_t [128ct][128B] hi; sub-block ctb = +ctb*8192 (reused as IMG)
#define LDS_HETL  58368
#define LDS_Q1P   74752    // [2][128] f
#define LDS_AP    75776
#define LDS_RP    76800
#define LDS_ALP   77824
#define LDS_ALI   78080
// overlays: H2H@25600(12800) H2L@38400(12800) after P4; SIG@0 ([50][128]f) in P5
#define K1F_LDS   78336

typedef __attribute__((ext_vector_type(8))) short bf16x8;
typedef __attribute__((ext_vector_type(4))) float f32x4;

__device__ __forceinline__ unsigned short f2bf(float f) {
  unsigned int u = __float_as_uint(f);
  unsigned int r = (u + 0x7FFFu + ((u >> 16) & 1u)) >> 16;
  return (unsigned short)r;
}
__device__ __forceinline__ float bf2f(unsigned short h) {
  return __uint_as_float(((unsigned int)h) << 16);
}
__device__ __forceinline__ void cvt4(float4 v, ushort4& hi, ushort4& lo) {
  unsigned short h0 = f2bf(v.x), h1 = f2bf(v.y), h2 = f2bf(v.z), h3 = f2bf(v.w);
  hi = make_ushort4(h0, h1, h2, h3);
  lo = make_ushort4(f2bf(v.x - bf2f(h0)), f2bf(v.y - bf2f(h1)),
                    f2bf(v.z - bf2f(h2)), f2bf(v.w - bf2f(h3)));
}
__device__ __forceinline__ void gl_lds16(const void* g, void* l) {
  __builtin_amdgcn_global_load_lds(
      (const __attribute__((address_space(1))) void*)g,
      (__attribute__((address_space(3))) void*)l, 16, 0, 0);
}
__device__ __forceinline__ float sigm(float x) { return 1.f/(1.f + __expf(-x)); }

// ================= k0: weight prep (unchanged) =================
__global__ void k0_prep(const float* __restrict__ w_ih, const float* __restrict__ w_hh,
                        const float* __restrict__ W_ein, const float* __restrict__ W_eout,
                        const float* __restrict__ W1, const float* __restrict__ W2,
                        const float* __restrict__ Wt, char* __restrict__ wsb)
{
  float* wsf = (float*)wsb;
  for (int i = blockIdx.x * blockDim.x + threadIdx.x; i < 262144; i += gridDim.x * blockDim.x) {
    int idx = i;
    if (idx < 16384) { int k = idx >> 7, c = idx & 127; wsf[idx] = W1[c*128 + k]; continue; }
    idx -= 16384;
    if (idx < 16384) { int k = idx >> 7, c = idx & 127; wsf[16384 + idx] = W2[c*128 + k]; continue; }
    idx -= 16384;
    if (idx < 32768) { int k = idx >> 7, c = idx & 127; wsf[32768 + idx] = Wt[c*256 + k]; continue; }
    idx -= 32768;
    if (idx < 32768) {
      int n = idx >> 7, k = idx & 127;
      float v = (n < 128) ? W_ein[n*128 + k] : W_eout[(n-128)*128 + k];
      unsigned short h = f2bf(v);
      *(unsigned short*)(wsb + WS_WEH + idx*2) = h;
      *(unsigned short*)(wsb + WS_WEL + idx*2) = f2bf(v - bf2f(h));
      continue;
    }
    idx -= 32768;
    if (idx < 147456) {
      int n = idx / 384, k = idx % 384;
      float v = (k < 256) ? w_ih[n*256 + k] : w_hh[n*128 + (k - 256)];
      unsigned short h = f2bf(v);
      *(unsigned short*)(wsb + WS_WCATH + idx*2) = h;
      *(unsigned short*)(wsb + WS_WCATL + idx*2) = f2bf(v - bf2f(h));
      continue;
    }
    idx -= 147456;
    {
      float v = W2[idx];
      unsigned short h = f2bf(v);
      *(unsigned short*)(wsb + WS_W2H + idx*2) = h;
      *(unsigned short*)(wsb + WS_W2L + idx*2) = f2bf(v - bf2f(h));
    }
  }
}

// ================= k1f: fused GNN+GRU+attention, 256 thr, 2 blk/CU =================
__global__ __launch_bounds__(256, 2) void k1f(const int* __restrict__ items,
    const float* __restrict__ A, const float* __restrict__ emb,
    const int* __restrict__ alias_in,
    const float* __restrict__ b_ein, const float* __restrict__ b_eout,
    const float* __restrict__ b_iah, const float* __restrict__ b_oah,
    const float* __restrict__ b_ih, const float* __restrict__ b_hh,
    const float* __restrict__ b1, const float* __restrict__ b2,
    const float* __restrict__ W3, const float* __restrict__ bt_,
    char* __restrict__ wsb)
{
  extern __shared__ char lds[];
  char* HH   = lds + LDS_HH;
  char* HL   = lds + LDS_HL;
  char* AIH  = lds + LDS_AIH;
  char* AIL  = lds + LDS_AIL;
  char* HETH = lds + LDS_HETH;
  char* HETL = lds + LDS_HETL;
  char* H2H  = lds + 25600;
  char* H2L  = lds + 38400;
  float* SIG = (float*)lds;
  float* Q1P = (float*)(lds + LDS_Q1P);
  float* AP  = (float*)(lds + LDS_AP);
  float* RP  = (float*)(lds + LDS_RP);
  float* ALP = (float*)(lds + LDS_ALP);
  int*   ALI = (int*)(lds + LDS_ALI);

  const int b = blockIdx.x, tid = threadIdx.x;
  const int lane = tid & 63, wid = tid >> 6, l15 = lane & 15, lq = lane >> 4;
  const float* Ab = A + (size_t)b*NN*100;

  // helper: recombined H2 value (after GRU)
  auto h2val = [&](int row, int k) -> float {
    unsigned byte = (unsigned)(row*256) + (((unsigned)(k*2)) ^ (((unsigned)(row&7)) << 4));
    return bf2f(*(const unsigned short*)(H2H + byte))
         + bf2f(*(const unsigned short*)(H2L + byte));
  };

  // stage A image for one sel
  auto stageA = [&](int sel) {
    for (int i = tid; i < 4096; i += 256) {
      int n = i >> 6, m = i & 63;
      float v = (n < 50 && m < 50) ? Ab[n*100 + sel*50 + m] : 0.f;
      unsigned short hi = f2bf(v);
      unsigned short lo = f2bf(v - bf2f(hi));
      unsigned adr = (unsigned)(n*128) + (((unsigned)(m*2)) ^ (((unsigned)(n&7)) << 4));
      *(unsigned short*)(AIH + adr) = hi;
      *(unsigned short*)(AIL + adr) = lo;
    }
  };

  // ---- P1: stage A0, gather emb -> HH/HL ----
  stageA(0);
  for (int i = tid; i < 1600; i += 256) {
    int row = i >> 5, part = i & 31;
    int it = items[b*NN + row];
    float4 v = *(const float4*)&emb[(size_t)it*128 + part*4];
    ushort4 h4v, g4v;
    cvt4(v, h4v, g4v);
    unsigned off = row*256 + (((unsigned)(part*8)) ^ (((unsigned)(row&7)) << 4));
    *(ushort4*)(HH + off) = h4v;
    *(ushort4*)(HL + off) = g4v;
  }
  if (tid < 64) ALI[tid] = (tid < LLn) ? alias_in[b*LLn + tid] : 0;
  __syncthreads();

  // ---- P2(half): he cols [half*128, half*128+128) -> HET (+ pad re-zero) ----
  auto p2 = [&](int half) {
    // zero K-pads m=50..63 (IMG stores clobbered them for half=1)
    for (int i = tid; i < 3584; i += 256) {
      int img = (i >= 1792), e = img ? i - 1792 : i;
      int ct = e / 14, m = 50 + e % 14;
      unsigned adr = (unsigned)(ct*128) + (((unsigned)(m*2)) ^ (((unsigned)(ct&7)) << 4));
      *(unsigned short*)((img ? HETL : HETH) + adr) = 0;
    }
    f32x4 a2[2][4];
#pragma unroll
    for (int j = 0; j < 2; ++j)
#pragma unroll
      for (int i = 0; i < 4; ++i) a2[j][i] = (f32x4){0,0,0,0};
#pragma unroll
    for (int s = 0; s < 4; ++s) {
      bf16x8 ah[4], al4[4];
#pragma unroll
      for (int i = 0; i < 4; ++i) {
        int row = i*16 + l15;
        unsigned off = row*256 + (((unsigned)(s*64 + lq*16)) ^ (((unsigned)(row&7)) << 4));
        ah[i]  = *(const bf16x8*)(HH + off);
        al4[i] = *(const bf16x8*)(HL + off);
      }
#pragma unroll
      for (int j = 0; j < 2; ++j) {
        int nc = wid*32 + j*16 + l15;
        unsigned boff = (unsigned)((half*128 + nc)*256 + s*64 + lq*16);
        bf16x8 bh = *(const bf16x8*)(wsb + WS_WEH + boff);
        bf16x8 bl = *(const bf16x8*)(wsb + WS_WEL + boff);
#pragma unroll
        for (int i = 0; i < 4; ++i) {
          a2[j][i] = __builtin_amdgcn_mfma_f32_16x16x32_bf16(ah[i], bh, a2[j][i], 0,0,0);
          a2[j][i] = __builtin_amdgcn_mfma_f32_16x16x32_bf16(ah[i], bl, a2[j][i], 0,0,0);
          a2[j][i] = __builtin_amdgcn_mfma_f32_16x16x32_bf16(al4[i], bh, a2[j][i], 0,0,0);
        }
      }
    }
#pragma unroll
    for (int j = 0; j < 2; ++j) {
      int nc = wid*32 + j*16 + l15;
      float bv = half ? b_eout[nc] : b_ein[nc];
#pragma unroll
      for (int i = 0; i < 4; ++i)
#pragma unroll
        for (int q = 0; q < 4; ++q) {
          int m = i*16 + lq*4 + q;
          if (m < 50) {
            float v = a2[j][i][q] + bv;
            unsigned short hi = f2bf(v);
            unsigned short lo = f2bf(v - bf2f(hi));
            unsigned adr = (unsigned)(nc*128) + (((unsigned)(m*2)) ^ (((unsigned)(nc&7)) << 4));
            *(unsigned short*)(HETH + adr) = hi;
            *(unsigned short*)(HETL + adr) = lo;
          }
        }
    }
  };

  // ---- P3(sel, ctb): IN cols [sel*128+ctb*64, +64) -> IMG over HET block ctb ----
  // restage: stage A(sel=1) after the internal sync (A0 reads complete)
  auto p3 = [&](int sel, int ctb, bool restage) {
    f32x4 acc[4];
#pragma unroll
    for (int i = 0; i < 4; ++i) acc[i] = (f32x4){0,0,0,0};
    const int ct = ctb*64 + wid*16 + l15;
#pragma unroll
    for (int s2 = 0; s2 < 2; ++s2) {
      unsigned badr = (unsigned)(ct*128) + (((unsigned)(s2*64 + lq*16)) ^ (((unsigned)(ct&7)) << 4));
      bf16x8 bh = *(const bf16x8*)(HETH + badr);
      bf16x8 bl = *(const bf16x8*)(HETL + badr);
#pragma unroll
      for (int i = 0; i < 4; ++i) {
        int n = i*16 + l15;
        unsigned aadr = (unsigned)(n*128) + (((unsigned)(s2*64 + lq*16)) ^ (((unsigned)(n&7)) << 4));
        bf16x8 ah  = *(const bf16x8*)(AIH + aadr);
        bf16x8 al4 = *(const bf16x8*)(AIL + aadr);
        acc[i] = __builtin_amdgcn_mfma_f32_16x16x32_bf16(ah, bh, acc[i], 0,0,0);
        acc[i] = __builtin_amdgcn_mfma_f32_16x16x32_bf16(ah, bl, acc[i], 0,0,0);
        acc[i] = __builtin_amdgcn_mfma_f32_16x16x32_bf16(al4, bh, acc[i], 0,0,0);
      }
    }
    __syncthreads();   // all HET/A reads done before overwrite
    if (restage) stageA(1);
    int cb = ctb*64 + wid*16 + l15;
    float bv = sel ? b_oah[cb] : b_iah[cb];
    char* dH = HETH + ctb*8192;
    char* dL = HETL + ctb*8192;
    int cw = wid*16 + l15;
#pragma unroll
    for (int i = 0; i < 4; ++i)
#pragma unroll
      for (int q = 0; q < 4; ++q) {
        int row = i*16 + lq*4 + q;
        float v = acc[i][q] + bv;
        unsigned short hi = f2bf(v);
        unsigned short lo = f2bf(v - bf2f(hi));
        unsigned adr = (unsigned)(row*128) + (((unsigned)(cw*2)) ^ (((unsigned)(row&7)) << 4));
        *(unsigned short*)(dH + adr) = hi;
        *(unsigned short*)(dL + adr) = lo;
      }
  };

  // ---- P4 accumulators: 32 f32x4 (N=96 cols/wave: 3 gates x 2 subtiles; M=64) ----
  f32x4 accR[2][4], accI[2][4], accNi[2][4], accNh[2][4];
#pragma unroll
  for (int j2 = 0; j2 < 2; ++j2)
#pragma unroll
    for (int i = 0; i < 4; ++i) {
      accR[j2][i] = (f32x4){0,0,0,0}; accI[j2][i] = (f32x4){0,0,0,0};
      accNi[j2][i] = (f32x4){0,0,0,0}; accNh[j2][i] = (f32x4){0,0,0,0};
    }

  auto p4 = [&](const char* AH, const char* AL, int stride, int kbyte, int nS, bool toNh) {
#pragma unroll
    for (int s = 0; s < 4; ++s) {
      if (s >= nS) break;
      bf16x8 ah[4], al4[4];
#pragma unroll
      for (int i = 0; i < 4; ++i) {
        int row = i*16 + l15;
        unsigned off = (unsigned)(row*stride) + (((unsigned)(s*64 + lq*16)) ^ (((unsigned)(row&7)) << 4));
        ah[i]  = *(const bf16x8*)(AH + off);
        al4[i] = *(const bf16x8*)(AL + off);
      }
#pragma unroll
      for (int g = 0; g < 3; ++g)
#pragma unroll
        for (int j2 = 0; j2 < 2; ++j2) {
          int n = g*128 + wid*32 + j2*16 + l15;
          unsigned boff = (unsigned)(n*768 + kbyte + s*64 + lq*16);
          bf16x8 bh = *(const bf16x8*)(wsb + WS_WCATH + boff);
          bf16x8 bl = *(const bf16x8*)(wsb + WS_WCATL + boff);
          f32x4* tgt = (g == 0) ? accR[j2] : (g == 1) ? accI[j2] : (toNh ? accNh[j2] : accNi[j2]);
#pragma unroll
          for (int i = 0; i < 4; ++i) {
            tgt[i] = __builtin_amdgcn_mfma_f32_16x16x32_bf16(ah[i], bh, tgt[i], 0,0,0);
            tgt[i] = __builtin_amdgcn_mfma_f32_16x16x32_bf16(ah[i], bl, tgt[i], 0,0,0);
            tgt[i] = __builtin_amdgcn_mfma_f32_16x16x32_bf16(al4[i], bh, tgt[i], 0,0,0);
          }
        }
    }
  };

  // ---- pipeline ----
  p2(0);                    __syncthreads();
  p3(0, 0, false);          __syncthreads();
  p4(HETH, HETL, 128, 0, 2, false);
  p3(0, 1, true);           __syncthreads();
  p4(HETH + 8192, HETL + 8192, 128, 128, 2, false);
  __syncthreads();          // IMG0b reads done before P2b rewrites HET
  p2(1);                    __syncthreads();
  p3(1, 0, false);          __syncthreads();
  p4(HETH, HETL, 128, 256, 2, false);
  p3(1, 1, false);          __syncthreads();
  p4(HETH + 8192, HETL + 8192, 128, 384, 2, false);
  p4(HH, HL, 256, 512, 4, true);
  __syncthreads();          // all IMG/HET reads done; H2 may overlay

  // ---- GRU epilogue -> H2 bf16 images ----
  {
#pragma unroll
    for (int j2 = 0; j2 < 2; ++j2) {
      int c = wid*32 + j2*16 + l15;
      float bir = b_ih[c], bii = b_ih[128+c], bin_ = b_ih[256+c];
      float bhr = b_hh[c], bhi = b_hh[128+c], bhn  = b_hh[256+c];
#pragma unroll
      for (int i = 0; i < 4; ++i)
#pragma unroll
        for (int q = 0; q < 4; ++q) {
          int row = i*16 + lq*4 + q;
          if (row < 50) {
            float rg = sigm(accR[j2][i][q] + bir + bhr);
            float ig = sigm(accI[j2][i][q] + bii + bhi);
            float ng_ = tanhf(accNi[j2][i][q] + bin_ + rg*(accNh[j2][i][q] + bhn));
            unsigned byte = (unsigned)(row*256) + (((unsigned)(c*2)) ^ (((unsigned)(row&7)) << 4));
            float h = bf2f(*(const unsigned short*)(HH + byte))
                    + bf2f(*(const unsigned short*)(HL + byte));
            float hn = ng_ + ig*(h - ng_);
            unsigned short hi = f2bf(hn);
            unsigned short lo = f2bf(hn - bf2f(hi));
            *(unsigned short*)(H2H + byte) = hi;
            *(unsigned short*)(H2L + byte) = lo;
          }
        }
    }
  }
  __syncthreads();

  // ---- P5 ----
  int cnt = 0;
  for (int l = 0; l < LLn; ++l) cnt += (ALI[l] > 0) ? 1 : 0;
  int last = cnt - 1; if (last < 0) last = LLn - 1;
  const int a_last = ALI[last];

  const int c = tid & 127, h2 = tid >> 7;
  const float* W1T = (const float*)(wsb + WS_W1T);
  const float* WtT = (const float*)(wsb + WS_WTT);

  { // q1 partial over k-half
    float q = 0.f;
    for (int k = h2*64; k < h2*64 + 64; ++k)
      q += h2val(a_last, k) * W1T[(k<<7) + c];
    Q1P[h2*128 + c] = q;
  }
  __syncthreads();

  { // q2 via MFMA (all 4 waves, 2 col-subtiles each)
    f32x4 qa[2][4];
#pragma unroll
    for (int j = 0; j < 2; ++j)
#pragma unroll
      for (int i = 0; i < 4; ++i) qa[j][i] = (f32x4){0,0,0,0};
#pragma unroll
    for (int s = 0; s < 4; ++s) {
      bf16x8 ah[4], al4[4];
#pragma unroll
      for (int i = 0; i < 4; ++i) {
        int ali = ALI[i*16 + l15];
        unsigned aadr = (unsigned)(ali*256) + (((unsigned)(s*64 + lq*16)) ^ (((unsigned)(ali&7)) << 4));
        ah[i]  = *(const bf16x8*)(H2H + aadr);
        al4[i] = *(const bf16x8*)(H2L + aadr);
      }
#pragma unroll
      for (int j = 0; j < 2; ++j) {
        int cq = wid*32 + j*16 + l15;
        unsigned boff = (unsigned)(cq*256 + s*64 + lq*16);
        bf16x8 bh = *(const bf16x8*)(wsb + WS_W2H + boff);
        bf16x8 bl = *(const bf16x8*)(wsb + WS_W2L + boff);
#pragma unroll
        for (int i = 0; i < 4; ++i) {
          qa[j][i] = __builtin_amdgcn_mfma_f32_16x16x32_bf16(ah[i], bh, qa[j][i], 0,0,0);
          qa[j][i] = __builtin_amdgcn_mfma_f32_16x16x32_bf16(ah[i], bl, qa[j][i], 0,0,0);
          qa[j][i] = __builtin_amdgcn_mfma_f32_16x16x32_bf16(al4[i], bh, qa[j][i], 0,0,0);
        }
      }
    }
    __syncthreads();   // Q1P read below; also SIG overlays HH after this point
#pragma unroll
    for (int j = 0; j < 2; ++j) {
      int cq = wid*32 + j*16 + l15;
      float q1c = Q1P[cq] + Q1P[128+cq] + b1[cq] + b2[cq];
#pragma unroll
      for (int i = 0; i < 4; ++i)
#pragma unroll
        for (int q = 0; q < 4; ++q) {
          int l = i*16 + lq*4 + q;
          if (l < 50) SIG[l*128 + cq] = sigm(q1c + qa[j][i][q]);
        }
    }
  }
  __syncthreads();

  if (tid < 200) { // alpha = sig @ W3, 4 threads/row
    int l = tid >> 2, qd = tid & 3;
    float sum = 0.f;
    for (int cc = qd*32; cc < qd*32 + 32; cc += 4) {
      float4 x = *(const float4*)&SIG[l*128 + cc];
      sum += x.x*W3[cc] + x.y*W3[cc+1] + x.z*W3[cc+2] + x.w*W3[cc+3];
    }
    sum += __shfl_xor(sum, 1);
    sum += __shfl_xor(sum, 2);
    if (qd == 0) ALP[l] = (ALI[l] > 0) ? sum : 0.f;
  }
  __syncthreads();

  { // a partial over l-half
    float acc = 0.f;
    int l0 = h2*25;
    for (int l = l0; l < l0 + 25; ++l)
      acc += ALP[l] * h2val(ALI[l], c);
    AP[h2*128 + c] = acc;
  }
  __syncthreads();

  { // final r partial over k-half
    float r = 0.f;
    for (int k = h2*64; k < h2*64 + 64; ++k) {
      float av = AP[k] + AP[128+k];
      r += av * WtT[(k<<7) + c] + h2val(a_last, k) * WtT[((128+k)<<7) + c];
    }
    RP[h2*128 + c] = r;
  }
  __syncthreads();

  if (tid < 128) {
    float r = bt_[c] + RP[c] + RP[128+c];
    int kh = c >> 6, kl = c & 63;
    unsigned int cb = (unsigned int)(kl*2) ^ (((unsigned int)(b & 7)) << 4);
    unsigned short hi = f2bf(r);
    unsigned short lo = f2bf(r - bf2f(hi));
    *(unsigned short*)(wsb + WS_AHI + kh*65536 + b*128 + cb) = hi;
    *(unsigned short*)(wsb + WS_ALO + kh*65536 + b*128 + cb) = lo;
  }
}

// ================= k2: scores GEMM — emb read once (E tiles resident) =============
__global__ __launch_bounds__(512) void k2_mfma(const float* __restrict__ emb,
                                               const char* __restrict__ wsb,
                                               float* __restrict__ out)
{
  extern __shared__ char ldsc[];
  char* AHI = ldsc;
  char* ALO = ldsc + 32768;
  char* EH0 = ldsc + 65536;
  char* EL0 = ldsc + 81920;
  char* EH1 = ldsc + 98304;
  char* EL1 = ldsc + 114688;

  const int tid  = threadIdx.x;
  const int lane = tid & 63;
  const int wid  = tid >> 6;
  const int wm   = wid >> 1;
  const int wn   = wid & 1;
  const int j0   = blockIdx.x * 128;
  const int l15  = lane & 15, lq = lane >> 4;

  // stage E for both kh (single emb read)
  for (int e = tid; e < 4096; e += 512) {
    int row = e >> 5, c4 = e & 31;
    int j = j0 + row; if (j > OUTN - 1) j = OUTN - 1;
    float4 v = *(const float4*)&emb[(size_t)(1 + j)*HD + c4*4];
    ushort4 hi4, lo4;
    cvt4(v, hi4, lo4);
    int kh = c4 >> 4, cc = c4 & 15;
    unsigned off = (unsigned)(row*128) + (((unsigned)(cc*8)) ^ (((unsigned)(row&7)) << 4));
    *(ushort4*)((kh ? EH1 : EH0) + off) = hi4;
    *(ushort4*)((kh ? EL1 : EL0) + off) = lo4;
  }

#pragma unroll
  for (int bi = 0; bi < 2; ++bi) {
    f32x4 acc[4][4];
#pragma unroll
    for (int i = 0; i < 4; ++i)
#pragma unroll
      for (int j = 0; j < 4; ++j) acc[i][j] = (f32x4){0.f, 0.f, 0.f, 0.f};

#pragma unroll
    for (int kh = 0; kh < 2; ++kh) {
      const char* srcH = wsb + WS_AHI + kh*65536 + bi*32768;
      const char* srcL = wsb + WS_ALO + kh*65536 + bi*32768;
#pragma unroll
      for (int r = 0; r < 4; ++r) {
        int off = (r*512 + tid) * 16;
        gl_lds16(srcH + off, AHI + off);
        gl_lds16(srcL + off, ALO + off);
      }
      __syncthreads();
      const char* EHI = kh ? EH1 : EH0;
      const char* ELO = kh ? EL1 : EL0;

#pragma unroll
      for (int s = 0; s < 2; ++s) {
        bf16x8 ah[4], al[4], bh[4], bl[4];
        const unsigned int cb = (unsigned int)(s*64 + (lq << 4));
#pragma unroll
        for (int i = 0; i < 4; ++i) {
          int row = wm*64 + i*16 + l15;
          unsigned int off = (unsigned int)(row*128) + (cb ^ (((unsigned int)(row&7)) << 4));
          ah[i] = *(const bf16x8*)(AHI + off);
          al[i] = *(const bf16x8*)(ALO + off);
        }
#pragma unroll
        for (int j = 0; j < 4; ++j) {
          int row = wn*64 + j*16 + l15;
          unsigned int off = (unsigned int)(row*128) + (cb ^ (((unsigned int)(row&7)) << 4));
          bh[j] = *(const bf16x8*)(EHI + off);
          bl[j] = *(const bf16x8*)(ELO + off);
        }
#pragma unroll
        for (int i = 0; i < 4; ++i)
#pragma unroll
          for (int j = 0; j < 4; ++j) {
            acc[i][j] = __builtin_amdgcn_mfma_f32_16x16x32_bf16(ah[i], bh[j], acc[i][j], 0, 0, 0);
            acc[i][j] = __builtin_amdgcn_mfma_f32_16x16x32_bf16(ah[i], bl[j], acc[i][j], 0, 0, 0);
            acc[i][j] = __builtin_amdgcn_mfma_f32_16x16x32_bf16(al[i], bh[j], acc[i][j], 0, 0, 0);
          }
      }
      __syncthreads();
    }

#pragma unroll
    for (int i = 0; i < 4; ++i) {
#pragma unroll
      for (int j = 0; j < 4; ++j) {
        int jj = j0 + wn*64 + j*16 + l15;
        if (jj < OUTN) {
          size_t rowbase = (size_t)(bi*256 + wm*64 + i*16 + lq*4);
#pragma unroll
          for (int q = 0; q < 4; ++q)
            out[(rowbase + q)*OUTN + jj] = acc[i][j][q];
        }
      }
    }
  }
}

extern "C" void kernel_launch(void* const* d_in, const int* in_sizes, int n_in,
                              void* d_out, int out_size, void* d_ws, size_t ws_size,
                              hipStream_t stream)
{
  const int*   items  = (const int*)  d_in[0];
  const float* A      = (const float*)d_in[1];
  const int*   alias  = (const int*)  d_in[2];
  const float* emb    = (const float*)d_in[3];
  const float* w_ih   = (const float*)d_in[4];
  const float* w_hh   = (const float*)d_in[5];
  const float* b_ih   = (const float*)d_in[6];
  const float* b_hh   = (const float*)d_in[7];
  const float* b_iah  = (const float*)d_in[8];
  const float* b_oah  = (const float*)d_in[9];
  const float* W_ein  = (const float*)d_in[10];
  const float* b_ein  = (const float*)d_in[11];
  const float* W_eout = (const float*)d_in[12];
  const float* b_eout = (const float*)d_in[13];
  const float* W1     = (const float*)d_in[14];
  const float* b1     = (const float*)d_in[15];
  const float* W2     = (const float*)d_in[16];
  const float* b2     = (const float*)d_in[17];
  const float* W3     = (const float*)d_in[18];
  const float* Wt     = (const float*)d_in[19];
  const float* bt_    = (const float*)d_in[20];

  char*  wsb  = (char*)d_ws;
  float* outf = (float*)d_out;

  k0_prep<<<240, 256, 0, stream>>>(w_ih, w_hh, W_ein, W_eout, W1, W2, Wt, wsb);

  k1f<<<NB, 256, K1F_LDS, stream>>>(items, A, emb, alias, b_ein, b_eout, b_iah, b_oah,
                                    b_ih, b_hh, b1, b2, W3, bt_, wsb);

  k2_mfma<<<dim3(782, 1), 512, 131072, stream>>>(emb, (const char*)d_ws, outf);
}

// Round 15
// 187.894 us; speedup vs baseline: 1.0735x; 1.0735x over previous
//
#include <hip/hip_runtime.h>

#define NB   512
#define NN   50
#define LLn  50
#define HD   128
#define OUTN 99999

// ---------------- ws byte offsets ----------------
#define WS_W1T   0         // fp32 [128][128] transposed
#define WS_W2T   65536     // fp32 [128][128] transposed (unused, kept)
#define WS_WTT   131072    // fp32 [256][128] transposed
#define WS_WEH   262144    // bf16 hi [256 n][128 k]
#define WS_WEL   327680
#define WS_WCATH 393216    // bf16 hi [384 n][384 k]
#define WS_WCATL 688128
#define WS_AHI   983040    // a-final hi image [2 kh][512 b][128 B]
#define WS_ALO   1114112
#define WS_W2H   1245184   // bf16 hi [128 n][128 k]
#define WS_W2L   1277952

typedef __attribute__((ext_vector_type(8))) short bf16x8;
typedef __attribute__((ext_vector_type(4))) float f32x4;

__device__ __forceinline__ unsigned short f2bf(float f) {
  unsigned int u = __float_as_uint(f);
  unsigned int r = (u + 0x7FFFu + ((u >> 16) & 1u)) >> 16;
  return (unsigned short)r;
}
__device__ __forceinline__ float bf2f(unsigned short h) {
  return __uint_as_float(((unsigned int)h) << 16);
}
__device__ __forceinline__ void cvt4(float4 v, ushort4& hi, ushort4& lo) {
  unsigned short h0 = f2bf(v.x), h1 = f2bf(v.y), h2 = f2bf(v.z), h3 = f2bf(v.w);
  hi = make_ushort4(h0, h1, h2, h3);
  lo = make_ushort4(f2bf(v.x - bf2f(h0)), f2bf(v.y - bf2f(h1)),
                    f2bf(v.z - bf2f(h2)), f2bf(v.w - bf2f(h3)));
}
__device__ __forceinline__ void gl_lds16(const void* g, void* l) {
  __builtin_amdgcn_global_load_lds(
      (const __attribute__((address_space(1))) void*)g,
      (__attribute__((address_space(3))) void*)l, 16, 0, 0);
}
__device__ __forceinline__ float sigm(float x) { return 1.f/(1.f + __expf(-x)); }

// ================= k0: weight prep (proven) =================
__global__ void k0_prep(const float* __restrict__ w_ih, const float* __restrict__ w_hh,
                        const float* __restrict__ W_ein, const float* __restrict__ W_eout,
                        const float* __restrict__ W1, const float* __restrict__ W2,
                        const float* __restrict__ Wt, char* __restrict__ wsb)
{
  float* wsf = (float*)wsb;
  for (int i = blockIdx.x * blockDim.x + threadIdx.x; i < 262144; i += gridDim.x * blockDim.x) {
    int idx = i;
    if (idx < 16384) { int k = idx >> 7, c = idx & 127; wsf[idx] = W1[c*128 + k]; continue; }
    idx -= 16384;
    if (idx < 16384) { int k = idx >> 7, c = idx & 127; wsf[16384 + idx] = W2[c*128 + k]; continue; }
    idx -= 16384;
    if (idx < 32768) { int k = idx >> 7, c = idx & 127; wsf[32768 + idx] = Wt[c*256 + k]; continue; }
    idx -= 32768;
    if (idx < 32768) {
      int n = idx >> 7, k = idx & 127;
      float v = (n < 128) ? W_ein[n*128 + k] : W_eout[(n-128)*128 + k];
      unsigned short h = f2bf(v);
      *(unsigned short*)(wsb + WS_WEH + idx*2) = h;
      *(unsigned short*)(wsb + WS_WEL + idx*2) = f2bf(v - bf2f(h));
      continue;
    }
    idx -= 32768;
    if (idx < 147456) {
      int n = idx / 384, k = idx % 384;
      float v = (k < 256) ? w_ih[n*256 + k] : w_hh[n*128 + (k - 256)];
      unsigned short h = f2bf(v);
      *(unsigned short*)(wsb + WS_WCATH + idx*2) = h;
      *(unsigned short*)(wsb + WS_WCATL + idx*2) = f2bf(v - bf2f(h));
      continue;
    }
    idx -= 147456;
    {
      float v = W2[idx];
      unsigned short h = f2bf(v);
      *(unsigned short*)(wsb + WS_W2H + idx*2) = h;
      *(unsigned short*)(wsb + WS_W2L + idx*2) = f2bf(v - bf2f(h));
    }
  }
}

// ================= k1f: fused per-sample GNN+GRU+attention (proven R13) ===========
__global__ __launch_bounds__(512) void k1f(const int* __restrict__ items,
    const float* __restrict__ A, const float* __restrict__ emb,
    const int* __restrict__ alias_in,
    const float* __restrict__ b_ein, const float* __restrict__ b_eout,
    const float* __restrict__ b_iah, const float* __restrict__ b_oah,
    const float* __restrict__ b_ih, const float* __restrict__ b_hh,
    const float* __restrict__ b1, const float* __restrict__ b2,
    const float* __restrict__ W3, const float* __restrict__ bt_,
    char* __restrict__ wsb)
{
  extern __shared__ char lds[];
  char*  IMG0H = lds;
  char*  IMG0L = lds + 16384;
  float* SIG   = (float*)lds;
  char*  HH    = lds + 32768;
  char*  HL    = lds + 49152;
  char*  HETH  = lds + 65536;
  char*  HETL  = lds + 98304;
  char*  IMG1H = lds + 65536;
  char*  IMG1L = lds + 81920;
  char*  H2H   = lds + 65536;
  char*  H2L   = lds + 81920;
  float* H2f   = (float*)(lds + 98304);
  float* Q1P   = (float*)(lds + 32768);
  float* AP    = (float*)(lds + 34816);
  float* RP    = (float*)(lds + 36864);
  float* ALP   = (float*)(lds + 38912);
  int*   ALI   = (int*)(lds + 39168);

  const int b = blockIdx.x, tid = threadIdx.x;
  const int lane = tid & 63, wid = tid >> 6, l15 = lane & 15, lq = lane >> 4;

  // ---- P1: zero he_t pads; build A images; gather emb -> HH/HL ----
  for (int i = tid; i < 7168; i += 512) {
    int bufsel = (i >= 3584), e = bufsel ? i - 3584 : i;
    int cc = e / 14, m = 50 + e % 14;
    unsigned adr = (unsigned)(cc*128) + (((unsigned)(m*2)) ^ (((unsigned)(cc&7)) << 4));
    *(unsigned short*)((bufsel ? HETL : HETH) + adr) = 0;
  }
  {
    const float* Ab = A + (size_t)b*NN*100;
    for (int i = tid; i < 8192; i += 512) {
      int sel = i >> 12, e = i & 4095, n = e >> 6, m = e & 63;
      float v = (n < 50 && m < 50) ? Ab[n*100 + sel*50 + m] : 0.f;
      unsigned short hi = f2bf(v);
      unsigned short lo = f2bf(v - bf2f(hi));
      unsigned adr = (unsigned)(n*128) + (((unsigned)(m*2)) ^ (((unsigned)(n&7)) << 4));
      *(unsigned short*)(lds + sel*16384 + adr) = hi;
      *(unsigned short*)(lds + sel*16384 + 8192 + adr) = lo;
    }
  }
  for (int i = tid; i < 2048; i += 512) {
    int row = i >> 5, part = i & 31;
    float4 v = make_float4(0.f,0.f,0.f,0.f);
    if (row < 50) {
      int it = items[b*NN + row];
      v = *(const float4*)&emb[(size_t)it*128 + part*4];
    }
    ushort4 h4v, g4v;
    cvt4(v, h4v, g4v);
    unsigned off = row*256 + (((unsigned)(part*8)) ^ (((unsigned)(row&7)) << 4));
    *(ushort4*)(HH + off) = h4v;
    *(ushort4*)(HL + off) = g4v;
  }
  __syncthreads();

  // ---- P2: he GEMM (M=64 m, N=256 c, K=128) -> transposed he_t images ----
  {
    f32x4 acc2[4][2];
#pragma unroll
    for (int i = 0; i < 4; ++i) { acc2[i][0] = (f32x4){0,0,0,0}; acc2[i][1] = (f32x4){0,0,0,0}; }
#pragma unroll
    for (int s = 0; s < 4; ++s) {
      bf16x8 ah[4], al[4];
#pragma unroll
      for (int i = 0; i < 4; ++i) {
        int row = i*16 + l15;
        unsigned off = row*256 + (((unsigned)(s*64 + lq*16)) ^ (((unsigned)(row&7)) << 4));
        ah[i] = *(const bf16x8*)(HH + off);
        al[i] = *(const bf16x8*)(HL + off);
      }
#pragma unroll
      for (int j = 0; j < 2; ++j) {
        int nc = wid*32 + j*16 + l15;
        unsigned boff = (unsigned)(nc*256 + s*64 + lq*16);
        bf16x8 bh = *(const bf16x8*)(wsb + WS_WEH + boff);
        bf16x8 bl = *(const bf16x8*)(wsb + WS_WEL + boff);
#pragma unroll
        for (int i = 0; i < 4; ++i) {
          acc2[i][j] = __builtin_amdgcn_mfma_f32_16x16x32_bf16(ah[i], bh, acc2[i][j], 0,0,0);
          acc2[i][j] = __builtin_amdgcn_mfma_f32_16x16x32_bf16(ah[i], bl, acc2[i][j], 0,0,0);
          acc2[i][j] = __builtin_amdgcn_mfma_f32_16x16x32_bf16(al[i], bh, acc2[i][j], 0,0,0);
        }
      }
    }
#pragma unroll
    for (int j = 0; j < 2; ++j) {
      int nc = wid*32 + j*16 + l15;
      float bv = (nc < 128) ? b_ein[nc] : b_eout[nc - 128];
#pragma unroll
      for (int i = 0; i < 4; ++i)
#pragma unroll
        for (int q = 0; q < 4; ++q) {
          int m = i*16 + lq*4 + q;
          if (m < 50) {
            float v = acc2[i][j][q] + bv;
            unsigned short hi = f2bf(v);
            unsigned short lo = f2bf(v - bf2f(hi));
            unsigned adr = (unsigned)(nc*128) + (((unsigned)(m*2)) ^ (((unsigned)(nc&7)) << 4));
            *(unsigned short*)(HETH + adr) = hi;
            *(unsigned short*)(HETL + adr) = lo;
          }
        }
    }
  }
  __syncthreads();

  // ---- P3: IN = A @ he via MFMA (M=64 n, N=128 c per sel, K=64 m) ----
  {
    const int c = wid*16 + l15;
    f32x4 accS[2][4];
#pragma unroll
    for (int sel = 0; sel < 2; ++sel)
#pragma unroll
      for (int i = 0; i < 4; ++i) accS[sel][i] = (f32x4){0,0,0,0};
#pragma unroll
    for (int sel = 0; sel < 2; ++sel) {
#pragma unroll
      for (int s2 = 0; s2 < 2; ++s2) {
        int ct = sel*128 + c;
        unsigned badr = (unsigned)(ct*128) + (((unsigned)(s2*64 + lq*16)) ^ (((unsigned)(ct&7)) << 4));
        bf16x8 bh = *(const bf16x8*)(HETH + badr);
        bf16x8 bl = *(const bf16x8*)(HETL + badr);
#pragma unroll
        for (int i = 0; i < 4; ++i) {
          int n = i*16 + l15;
          unsigned aadr = (unsigned)(n*128) + (((unsigned)(s2*64 + lq*16)) ^ (((unsigned)(n&7)) << 4));
          bf16x8 ah = *(const bf16x8*)(lds + sel*16384 + aadr);
          bf16x8 al = *(const bf16x8*)(lds + sel*16384 + 8192 + aadr);
          accS[sel][i] = __builtin_amdgcn_mfma_f32_16x16x32_bf16(ah, bh, accS[sel][i], 0,0,0);
          accS[sel][i] = __builtin_amdgcn_mfma_f32_16x16x32_bf16(ah, bl, accS[sel][i], 0,0,0);
          accS[sel][i] = __builtin_amdgcn_mfma_f32_16x16x32_bf16(al, bh, accS[sel][i], 0,0,0);
        }
      }
    }
    __syncthreads();   // AI & he_t reads done; safe to overwrite with IMG0/IMG1
#pragma unroll
    for (int sel = 0; sel < 2; ++sel) {
      float bv = sel ? b_oah[c] : b_iah[c];
      char* dH = sel ? IMG1H : IMG0H;
      char* dL = sel ? IMG1L : IMG0L;
#pragma unroll
      for (int i = 0; i < 4; ++i)
#pragma unroll
        for (int q = 0; q < 4; ++q) {
          int row = i*16 + lq*4 + q;
          float v = accS[sel][i][q] + bv;
          unsigned short hi = f2bf(v);
          unsigned short lo = f2bf(v - bf2f(hi));
          unsigned adr = row*256 + (((unsigned)(c*2)) ^ (((unsigned)(row&7)) << 4));
          *(unsigned short*)(dH + adr) = hi;
          *(unsigned short*)(dL + adr) = lo;
        }
    }
  }
  __syncthreads();

  // ---- P4: cat-GEMM [IN0|IN1|H] @ [w_ih|w_hh]^T + GRU epilogue ----
  f32x4 accRI[4][2], accNi[4], accNh[4];
#pragma unroll
  for (int i = 0; i < 4; ++i) {
    accRI[i][0] = (f32x4){0,0,0,0}; accRI[i][1] = (f32x4){0,0,0,0};
    accNi[i] = (f32x4){0,0,0,0};    accNh[i] = (f32x4){0,0,0,0};
  }
  const int nl = wid*16 + l15;

  auto cat_gemm = [&](const char* AH, const char* AL, int kh, bool toNh) {
#pragma unroll
    for (int s = 0; s < 4; ++s) {
      bf16x8 ah[4], al[4];
#pragma unroll
      for (int i = 0; i < 4; ++i) {
        int row = i*16 + l15;
        unsigned off = row*256 + (((unsigned)(s*64 + lq*16)) ^ (((unsigned)(row&7)) << 4));
        ah[i] = *(const bf16x8*)(AH + off);
        al[i] = *(const bf16x8*)(AL + off);
      }
#pragma unroll
      for (int g = 0; g < 2; ++g) {
        unsigned boff = (unsigned)((g*128 + nl)*768 + kh*256 + s*64 + lq*16);
        bf16x8 bh = *(const bf16x8*)(wsb + WS_WCATH + boff);
        bf16x8 bl = *(const bf16x8*)(wsb + WS_WCATL + boff);
#pragma unroll
        for (int i = 0; i < 4; ++i) {
          accRI[i][g] = __builtin_amdgcn_mfma_f32_16x16x32_bf16(ah[i], bh, accRI[i][g], 0,0,0);
          accRI[i][g] = __builtin_amdgcn_mfma_f32_16x16x32_bf16(ah[i], bl, accRI[i][g], 0,0,0);
          accRI[i][g] = __builtin_amdgcn_mfma_f32_16x16x32_bf16(al[i], bh, accRI[i][g], 0,0,0);
        }
      }
      {
        unsigned boff = (unsigned)((256 + nl)*768 + kh*256 + s*64 + lq*16);
        bf16x8 bh = *(const bf16x8*)(wsb + WS_WCATH + boff);
        bf16x8 bl = *(const bf16x8*)(wsb + WS_WCATL + boff);
        if (toNh) {
#pragma unroll
          for (int i = 0; i < 4; ++i) {
            accNh[i] = __builtin_amdgcn_mfma_f32_16x16x32_bf16(ah[i], bh, accNh[i], 0,0,0);
            accNh[i] = __builtin_amdgcn_mfma_f32_16x16x32_bf16(ah[i], bl, accNh[i], 0,0,0);
            accNh[i] = __builtin_amdgcn_mfma_f32_16x16x32_bf16(al[i], bh, accNh[i], 0,0,0);
          }
        } else {
#pragma unroll
          for (int i = 0; i < 4; ++i) {
            accNi[i] = __builtin_amdgcn_mfma_f32_16x16x32_bf16(ah[i], bh, accNi[i], 0,0,0);
            accNi[i] = __builtin_amdgcn_mfma_f32_16x16x32_bf16(ah[i], bl, accNi[i], 0,0,0);
            accNi[i] = __builtin_amdgcn_mfma_f32_16x16x32_bf16(al[i], bh, accNi[i], 0,0,0);
          }
        }
      }
    }
  };

  cat_gemm(IMG0H, IMG0L, 0, false);
  cat_gemm(IMG1H, IMG1L, 1, false);
  cat_gemm(HH,    HL,    2, true);
  __syncthreads();   // IMG1 reads done before H2 images overlay

  // ---- GRU pointwise epilogue -> H2f plain + H2 bf16 images ----
  {
    const int c = nl;
    float bir = b_ih[c], bii = b_ih[128+c], bin_ = b_ih[256+c];
    float bhr = b_hh[c], bhi = b_hh[128+c], bhn  = b_hh[256+c];
#pragma unroll
    for (int i = 0; i < 4; ++i) {
#pragma unroll
      for (int q = 0; q < 4; ++q) {
        int row = i*16 + lq*4 + q;
        if (row < 50) {
          float rg = sigm(accRI[i][0][q] + bir + bhr);
          float ig = sigm(accRI[i][1][q] + bii + bhi);
          float ng_ = tanhf(accNi[i][q] + bin_ + rg*(accNh[i][q] + bhn));
          unsigned byte = row*256 + (((unsigned)(c*2)) ^ (((unsigned)(row&7)) << 4));
          float h = bf2f(*(const unsigned short*)(HH + byte))
                  + bf2f(*(const unsigned short*)(HL + byte));
          float hn = ng_ + ig*(h - ng_);
          H2f[row*128 + c] = hn;
          unsigned short hi = f2bf(hn);
          unsigned short lo = f2bf(hn - bf2f(hi));
          *(unsigned short*)(H2H + byte) = hi;
          *(unsigned short*)(H2L + byte) = lo;
        }
      }
    }
  }
  __syncthreads();   // HH reads done -> small buffers may overlay

  if (tid < 64) ALI[tid] = (tid < LLn) ? alias_in[b*LLn + tid] : 0;
  __syncthreads();

  // ---- P5: attention readout ----
  int cnt = 0;
  for (int l = 0; l < LLn; ++l) cnt += (ALI[l] > 0) ? 1 : 0;
  int last = cnt - 1; if (last < 0) last = LLn - 1;
  const int a_last = ALI[last];

  const int c = tid & 127, h4 = tid >> 7;
  const float* W1T = (const float*)(wsb + WS_W1T);
  const float* WtT = (const float*)(wsb + WS_WTT);

  { // q1 partial over k-quarter (VALU, small)
    float q = 0.f;
    for (int k = h4*32; k < h4*32 + 32; k += 4) {
      float4 x = *(const float4*)&H2f[a_last*128 + k];
      q += x.x*W1T[(k<<7)+c] + x.y*W1T[((k+1)<<7)+c]
         + x.z*W1T[((k+2)<<7)+c] + x.w*W1T[((k+3)<<7)+c];
    }
    Q1P[h4*128 + c] = q;
  }
  __syncthreads();

  { // q2 via MFMA: rows l (gather alias), cols c, K=128
    const int cq = nl;
    f32x4 qa[4];
#pragma unroll
    for (int i = 0; i < 4; ++i) qa[i] = (f32x4){0,0,0,0};
#pragma unroll
    for (int s = 0; s < 4; ++s) {
      unsigned boff = (unsigned)(cq*256 + s*64 + lq*16);
      bf16x8 bh = *(const bf16x8*)(wsb + WS_W2H + boff);
      bf16x8 bl = *(const bf16x8*)(wsb + WS_W2L + boff);
#pragma unroll
      for (int i = 0; i < 4; ++i) {
        int ali = ALI[i*16 + l15];
        unsigned aadr = ali*256 + (((unsigned)(s*64 + lq*16)) ^ (((unsigned)(ali&7)) << 4));
        bf16x8 ah = *(const bf16x8*)(H2H + aadr);
        bf16x8 al = *(const bf16x8*)(H2L + aadr);
        qa[i] = __builtin_amdgcn_mfma_f32_16x16x32_bf16(ah, bh, qa[i], 0,0,0);
        qa[i] = __builtin_amdgcn_mfma_f32_16x16x32_bf16(ah, bl, qa[i], 0,0,0);
        qa[i] = __builtin_amdgcn_mfma_f32_16x16x32_bf16(al, bh, qa[i], 0,0,0);
      }
    }
    float q1c = Q1P[cq] + Q1P[128+cq] + Q1P[256+cq] + Q1P[384+cq] + b1[cq] + b2[cq];
#pragma unroll
    for (int i = 0; i < 4; ++i)
#pragma unroll
      for (int q = 0; q < 4; ++q) {
        int l = i*16 + lq*4 + q;
        if (l < 50) SIG[l*128 + cq] = sigm(q1c + qa[i][q]);
      }
  }
  __syncthreads();

  if (tid < 400) { // alpha = sig @ W3, 8 threads/row
    int l = tid >> 3, qd = tid & 7;
    float sum = 0.f;
    for (int cc = qd*16; cc < qd*16 + 16; cc += 4) {
      float4 x = *(const float4*)&SIG[l*128 + cc];
      sum += x.x*W3[cc] + x.y*W3[cc+1] + x.z*W3[cc+2] + x.w*W3[cc+3];
    }
    sum += __shfl_xor(sum, 1);
    sum += __shfl_xor(sum, 2);
    sum += __shfl_xor(sum, 4);
    if (qd == 0) ALP[l] = (ALI[l] > 0) ? sum : 0.f;
  }
  __syncthreads();

  { // a partial over l-quarter
    float acc = 0.f;
    int l0 = h4*13, l1 = l0 + 13; if (l1 > LLn) l1 = LLn;
    for (int l = l0; l < l1; ++l)
      acc += ALP[l] * H2f[ALI[l]*128 + c];
    AP[h4*128 + c] = acc;
  }
  __syncthreads();

  { // final r partial over k-quarter
    float r = 0.f;
    for (int k = h4*32; k < h4*32 + 32; ++k) {
      float av = AP[k] + AP[128+k] + AP[256+k] + AP[384+k];
      r += av * WtT[(k<<7) + c] + H2f[a_last*128 + k] * WtT[((128+k)<<7) + c];
    }
    RP[h4*128 + c] = r;
  }
  __syncthreads();

  if (tid < 128) {
    float r = bt_[c] + RP[c] + RP[128+c] + RP[256+c] + RP[384+c];
    int kh = c >> 6, kl = c & 63;
    unsigned int cb = (unsigned int)(kl*2) ^ (((unsigned int)(b & 7)) << 4);
    unsigned short hi = f2bf(r);
    unsigned short lo = f2bf(r - bf2f(hi));
    *(unsigned short*)(wsb + WS_AHI + kh*65536 + b*128 + cb) = hi;
    *(unsigned short*)(wsb + WS_ALO + kh*65536 + b*128 + cb) = lo;
  }
}

// ================= k2: E staged once, writes at end (old barrier discipline) ======
__global__ __launch_bounds__(512) void k2_mfma(const float* __restrict__ emb,
                                               const char* __restrict__ wsb,
                                               float* __restrict__ out)
{
  extern __shared__ char ldsc[];
  char* AHI = ldsc;
  char* ALO = ldsc + 32768;
  char* EH0 = ldsc + 65536;
  char* EL0 = ldsc + 81920;
  char* EH1 = ldsc + 98304;
  char* EL1 = ldsc + 114688;

  const int tid  = threadIdx.x;
  const int lane = tid & 63;
  const int wid  = tid >> 6;
  const int wm   = wid >> 1;
  const int wn   = wid & 1;
  const int j0   = blockIdx.x * 128;
  const int l15  = lane & 15, lq = lane >> 4;

  // stage E for both kh (single emb read)
  for (int e = tid; e < 4096; e += 512) {
    int row = e >> 5, c4 = e & 31;
    int j = j0 + row; if (j > OUTN - 1) j = OUTN - 1;
    float4 v = *(const float4*)&emb[(size_t)(1 + j)*HD + c4*4];
    ushort4 hi4, lo4;
    cvt4(v, hi4, lo4);
    int kh = c4 >> 4, cc = c4 & 15;
    unsigned off = (unsigned)(row*128) + (((unsigned)(cc*8)) ^ (((unsigned)(row&7)) << 4));
    *(ushort4*)((kh ? EH1 : EH0) + off) = hi4;
    *(ushort4*)((kh ? EL1 : EL0) + off) = lo4;
  }

  f32x4 acc[2][4][4];
#pragma unroll
  for (int bi = 0; bi < 2; ++bi)
#pragma unroll
    for (int i = 0; i < 4; ++i)
#pragma unroll
      for (int j = 0; j < 4; ++j) acc[bi][i][j] = (f32x4){0.f, 0.f, 0.f, 0.f};

  for (int kh = 0; kh < 2; ++kh) {
    const char* EHI = kh ? EH1 : EH0;
    const char* ELO = kh ? EL1 : EL0;
#pragma unroll
    for (int bi = 0; bi < 2; ++bi) {
      const char* srcH = wsb + WS_AHI + kh*65536 + bi*32768;
      const char* srcL = wsb + WS_ALO + kh*65536 + bi*32768;
#pragma unroll
      for (int r = 0; r < 4; ++r) {
        int off = (r*512 + tid) * 16;
        gl_lds16(srcH + off, AHI + off);
        gl_lds16(srcL + off, ALO + off);
      }
      __syncthreads();

#pragma unroll
      for (int s = 0; s < 2; ++s) {
        bf16x8 ah[4], al[4], bh[4], bl[4];
        const unsigned int cb = (unsigned int)(s*64 + (lq << 4));
#pragma unroll
        for (int i = 0; i < 4; ++i) {
          int row = wm*64 + i*16 + l15;
          unsigned int off = (unsigned int)(row*128) + (cb ^ (((unsigned int)(row&7)) << 4));
          ah[i] = *(const bf16x8*)(AHI + off);
          al[i] = *(const bf16x8*)(ALO + off);
        }
#pragma unroll
        for (int j = 0; j < 4; ++j) {
          int row = wn*64 + j*16 + l15;
          unsigned int off = (unsigned int)(row*128) + (cb ^ (((unsigned int)(row&7)) << 4));
          bh[j] = *(const bf16x8*)(EHI + off);
          bl[j] = *(const bf16x8*)(ELO + off);
        }
#pragma unroll
        for (int i = 0; i < 4; ++i)
#pragma unroll
          for (int j = 0; j < 4; ++j) {
            acc[bi][i][j] = __builtin_amdgcn_mfma_f32_16x16x32_bf16(ah[i], bh[j], acc[bi][i][j], 0, 0, 0);
            acc[bi][i][j] = __builtin_amdgcn_mfma_f32_16x16x32_bf16(ah[i], bl[j], acc[bi][i][j], 0, 0, 0);
            acc[bi][i][j] = __builtin_amdgcn_mfma_f32_16x16x32_bf16(al[i], bh[j], acc[bi][i][j], 0, 0, 0);
          }
      }
      __syncthreads();
    }
  }

  // epilogue: all stores after the final barrier (no mid-kernel write drain)
#pragma unroll
  for (int bi = 0; bi < 2; ++bi)
#pragma unroll
    for (int i = 0; i < 4; ++i) {
#pragma unroll
      for (int j = 0; j < 4; ++j) {
        int jj = j0 + wn*64 + j*16 + l15;
        if (jj < OUTN) {
          size_t rowbase = (size_t)(bi*256 + wm*64 + i*16 + lq*4);
#pragma unroll
          for (int q = 0; q < 4; ++q)
            out[(rowbase + q)*OUTN + jj] = acc[bi][i][j][q];
        }
      }
    }
}

extern "C" void kernel_launch(void* const* d_in, const int* in_sizes, int n_in,
                              void* d_out, int out_size, void* d_ws, size_t ws_size,
                              hipStream_t stream)
{
  const int*   items  = (const int*)  d_in[0];
  const float* A      = (const float*)d_in[1];
  const int*   alias  = (const int*)  d_in[2];
  const float* emb    = (const float*)d_in[3];
  const float* w_ih   = (const float*)d_in[4];
  const float* w_hh   = (const float*)d_in[5];
  const float* b_ih   = (const float*)d_in[6];
  const float* b_hh   = (const float*)d_in[7];
  const float* b_iah  = (const float*)d_in[8];
  const float* b_oah  = (const float*)d_in[9];
  const float* W_ein  = (const float*)d_in[10];
  const float* b_ein  = (const float*)d_in[11];
  const float* W_eout = (const float*)d_in[12];
  const float* b_eout = (const float*)d_in[13];
  const float* W1     = (const float*)d_in[14];
  const float* b1     = (const float*)d_in[15];
  const float* W2     = (const float*)d_in[16];
  const float* b2     = (const float*)d_in[17];
  const float* W3     = (const float*)d_in[18];
  const float* Wt     = (const float*)d_in[19];
  const float* bt_    = (const float*)d_in[20];

  char*  wsb  = (char*)d_ws;
  float* outf = (float*)d_out;

  k0_prep<<<240, 256, 0, stream>>>(w_ih, w_hh, W_ein, W_eout, W1, W2, Wt, wsb);

  k1f<<<NB, 512, 131072, stream>>>(items, A, emb, alias, b_ein, b_eout, b_iah, b_oah,
                                   b_ih, b_hh, b1, b2, W3, bt_, wsb);

  k2_mfma<<<dim3(782, 1), 512, 131072, stream>>>(emb, (const char*)d_ws, outf);
}

// Round 16
// 181.744 us; speedup vs baseline: 1.1098x; 1.0338x over previous
//
#include <hip/hip_runtime.h>

#define NB   512
#define NN   50
#define LLn  50
#define HD   128
#define OUTN 99999

// ---------------- ws byte offsets ----------------
#define WS_W1T   0         // fp32 [128][128] transposed
#define WS_W2T   65536     // fp32 [128][128] transposed (unused, kept)
#define WS_WTT   131072    // fp32 [256][128] transposed
#define WS_WEH   262144    // bf16 hi [256 n][128 k]
#define WS_WEL   327680
#define WS_WCATH 393216    // bf16 hi [384 n][384 k]
#define WS_WCATL 688128
#define WS_AHI   983040    // a-final hi image [2 kh][512 b][128 B]
#define WS_ALO   1114112
#define WS_W2H   1245184   // bf16 hi [128 n][128 k]
#define WS_W2L   1277952

// ---------------- k1f LDS (131072 B, 1 blk/CU, 512 thr = 8 waves) ----------------
// 0      AI0H 8K | AI0L 8K | AI1H 8K | AI1L 8K  -> after P3: IMG0H/IMG0L; P5: SIG
// 32768  HH [64][256B] | 49152 HL               -> P5 small: Q1P@32768 AP@34816
//                                                  RP@36864 ALP@38912 ALI@39168
// 65536  HETH | 98304 HETL                      -> after P3: IMG1H@65536, IMG1L@81920
//                                               -> after P4: H2H@65536, H2L@81920,
//                                                  H2f@98304 [50][128]f

typedef __attribute__((ext_vector_type(8))) short bf16x8;
typedef __attribute__((ext_vector_type(4))) float f32x4;

__device__ __forceinline__ unsigned short f2bf(float f) {
  unsigned int u = __float_as_uint(f);
  unsigned int r = (u + 0x7FFFu + ((u >> 16) & 1u)) >> 16;
  return (unsigned short)r;
}
__device__ __forceinline__ float bf2f(unsigned short h) {
  return __uint_as_float(((unsigned int)h) << 16);
}
__device__ __forceinline__ void cvt4(float4 v, ushort4& hi, ushort4& lo) {
  unsigned short h0 = f2bf(v.x), h1 = f2bf(v.y), h2 = f2bf(v.z), h3 = f2bf(v.w);
  hi = make_ushort4(h0, h1, h2, h3);
  lo = make_ushort4(f2bf(v.x - bf2f(h0)), f2bf(v.y - bf2f(h1)),
                    f2bf(v.z - bf2f(h2)), f2bf(v.w - bf2f(h3)));
}
__device__ __forceinline__ void gl_lds16(const void* g, void* l) {
  __builtin_amdgcn_global_load_lds(
      (const __attribute__((address_space(1))) void*)g,
      (__attribute__((address_space(3))) void*)l, 16, 0, 0);
}
__device__ __forceinline__ float sigm(float x) { return 1.f/(1.f + __expf(-x)); }

// ================= k0: weight prep =================
__global__ void k0_prep(const float* __restrict__ w_ih, const float* __restrict__ w_hh,
                        const float* __restrict__ W_ein, const float* __restrict__ W_eout,
                        const float* __restrict__ W1, const float* __restrict__ W2,
                        const float* __restrict__ Wt, char* __restrict__ wsb)
{
  float* wsf = (float*)wsb;
  for (int i = blockIdx.x * blockDim.x + threadIdx.x; i < 262144; i += gridDim.x * blockDim.x) {
    int idx = i;
    if (idx < 16384) { int k = idx >> 7, c = idx & 127; wsf[idx] = W1[c*128 + k]; continue; }
    idx -= 16384;
    if (idx < 16384) { int k = idx >> 7, c = idx & 127; wsf[16384 + idx] = W2[c*128 + k]; continue; }
    idx -= 16384;
    if (idx < 32768) { int k = idx >> 7, c = idx & 127; wsf[32768 + idx] = Wt[c*256 + k]; continue; }
    idx -= 32768;
    if (idx < 32768) {
      int n = idx >> 7, k = idx & 127;
      float v = (n < 128) ? W_ein[n*128 + k] : W_eout[(n-128)*128 + k];
      unsigned short h = f2bf(v);
      *(unsigned short*)(wsb + WS_WEH + idx*2) = h;
      *(unsigned short*)(wsb + WS_WEL + idx*2) = f2bf(v - bf2f(h));
      continue;
    }
    idx -= 32768;
    if (idx < 147456) {
      int n = idx / 384, k = idx % 384;
      float v = (k < 256) ? w_ih[n*256 + k] : w_hh[n*128 + (k - 256)];
      unsigned short h = f2bf(v);
      *(unsigned short*)(wsb + WS_WCATH + idx*2) = h;
      *(unsigned short*)(wsb + WS_WCATL + idx*2) = f2bf(v - bf2f(h));
      continue;
    }
    idx -= 147456;
    {
      float v = W2[idx];
      unsigned short h = f2bf(v);
      *(unsigned short*)(wsb + WS_W2H + idx*2) = h;
      *(unsigned short*)(wsb + WS_W2L + idx*2) = f2bf(v - bf2f(h));
    }
  }
}

// ================= k1f: fused per-sample GNN+GRU+attention (proven 181 µs) ========
__global__ __launch_bounds__(512) void k1f(const int* __restrict__ items,
    const float* __restrict__ A, const float* __restrict__ emb,
    const int* __restrict__ alias_in,
    const float* __restrict__ b_ein, const float* __restrict__ b_eout,
    const float* __restrict__ b_iah, const float* __restrict__ b_oah,
    const float* __restrict__ b_ih, const float* __restrict__ b_hh,
    const float* __restrict__ b1, const float* __restrict__ b2,
    const float* __restrict__ W3, const float* __restrict__ bt_,
    char* __restrict__ wsb)
{
  extern __shared__ char lds[];
  char*  IMG0H = lds;
  char*  IMG0L = lds + 16384;
  float* SIG   = (float*)lds;
  char*  HH    = lds + 32768;
  char*  HL    = lds + 49152;
  char*  HETH  = lds + 65536;
  char*  HETL  = lds + 98304;
  char*  IMG1H = lds + 65536;
  char*  IMG1L = lds + 81920;
  char*  H2H   = lds + 65536;
  char*  H2L   = lds + 81920;
  float* H2f   = (float*)(lds + 98304);
  float* Q1P   = (float*)(lds + 32768);
  float* AP    = (float*)(lds + 34816);
  float* RP    = (float*)(lds + 36864);
  float* ALP   = (float*)(lds + 38912);
  int*   ALI   = (int*)(lds + 39168);

  const int b = blockIdx.x, tid = threadIdx.x;
  const int lane = tid & 63, wid = tid >> 6, l15 = lane & 15, lq = lane >> 4;

  // ---- P1: zero he_t pads; build A images; gather emb -> HH/HL ----
  for (int i = tid; i < 7168; i += 512) {
    int bufsel = (i >= 3584), e = bufsel ? i - 3584 : i;
    int cc = e / 14, m = 50 + e % 14;
    unsigned adr = (unsigned)(cc*128) + (((unsigned)(m*2)) ^ (((unsigned)(cc&7)) << 4));
    *(unsigned short*)((bufsel ? HETL : HETH) + adr) = 0;
  }
  {
    const float* Ab = A + (size_t)b*NN*100;
    for (int i = tid; i < 8192; i += 512) {
      int sel = i >> 12, e = i & 4095, n = e >> 6, m = e & 63;
      float v = (n < 50 && m < 50) ? Ab[n*100 + sel*50 + m] : 0.f;
      unsigned short hi = f2bf(v);
      unsigned short lo = f2bf(v - bf2f(hi));
      unsigned adr = (unsigned)(n*128) + (((unsigned)(m*2)) ^ (((unsigned)(n&7)) << 4));
      *(unsigned short*)(lds + sel*16384 + adr) = hi;
      *(unsigned short*)(lds + sel*16384 + 8192 + adr) = lo;
    }
  }
  for (int i = tid; i < 2048; i += 512) {
    int row = i >> 5, part = i & 31;
    float4 v = make_float4(0.f,0.f,0.f,0.f);
    if (row < 50) {
      int it = items[b*NN + row];
      v = *(const float4*)&emb[(size_t)it*128 + part*4];
    }
    ushort4 h4v, g4v;
    cvt4(v, h4v, g4v);
    unsigned off = row*256 + (((unsigned)(part*8)) ^ (((unsigned)(row&7)) << 4));
    *(ushort4*)(HH + off) = h4v;
    *(ushort4*)(HL + off) = g4v;
  }
  __syncthreads();

  // ---- P2: he GEMM (M=64 m, N=256 c, K=128) -> transposed he_t images ----
  {
    f32x4 acc2[4][2];
#pragma unroll
    for (int i = 0; i < 4; ++i) { acc2[i][0] = (f32x4){0,0,0,0}; acc2[i][1] = (f32x4){0,0,0,0}; }
    for (int s = 0; s < 4; ++s) {
      bf16x8 ah[4], al[4];
#pragma unroll
      for (int i = 0; i < 4; ++i) {
        int row = i*16 + l15;
        unsigned off = row*256 + (((unsigned)(s*64 + lq*16)) ^ (((unsigned)(row&7)) << 4));
        ah[i] = *(const bf16x8*)(HH + off);
        al[i] = *(const bf16x8*)(HL + off);
      }
#pragma unroll
      for (int j = 0; j < 2; ++j) {
        int nc = wid*32 + j*16 + l15;
        unsigned boff = (unsigned)(nc*256 + s*64 + lq*16);
        bf16x8 bh = *(const bf16x8*)(wsb + WS_WEH + boff);
        bf16x8 bl = *(const bf16x8*)(wsb + WS_WEL + boff);
#pragma unroll
        for (int i = 0; i < 4; ++i) {
          acc2[i][j] = __builtin_amdgcn_mfma_f32_16x16x32_bf16(ah[i], bh, acc2[i][j], 0,0,0);
          acc2[i][j] = __builtin_amdgcn_mfma_f32_16x16x32_bf16(ah[i], bl, acc2[i][j], 0,0,0);
          acc2[i][j] = __builtin_amdgcn_mfma_f32_16x16x32_bf16(al[i], bh, acc2[i][j], 0,0,0);
        }
      }
    }
#pragma unroll
    for (int j = 0; j < 2; ++j) {
      int nc = wid*32 + j*16 + l15;
      float bv = (nc < 128) ? b_ein[nc] : b_eout[nc - 128];
#pragma unroll
      for (int i = 0; i < 4; ++i)
#pragma unroll
        for (int q = 0; q < 4; ++q) {
          int m = i*16 + lq*4 + q;
          if (m < 50) {
            float v = acc2[i][j][q] + bv;
            unsigned short hi = f2bf(v);
            unsigned short lo = f2bf(v - bf2f(hi));
            unsigned adr = (unsigned)(nc*128) + (((unsigned)(m*2)) ^ (((unsigned)(nc&7)) << 4));
            *(unsigned short*)(HETH + adr) = hi;
            *(unsigned short*)(HETL + adr) = lo;
          }
        }
    }
  }
  __syncthreads();

  // ---- P3: IN = A @ he via MFMA (M=64 n, N=128 c per sel, K=64 m) ----
  {
    const int c = wid*16 + l15;
    f32x4 accS[2][4];
#pragma unroll
    for (int sel = 0; sel < 2; ++sel)
#pragma unroll
      for (int i = 0; i < 4; ++i) accS[sel][i] = (f32x4){0,0,0,0};
#pragma unroll
    for (int sel = 0; sel < 2; ++sel) {
#pragma unroll
      for (int s2 = 0; s2 < 2; ++s2) {
        int ct = sel*128 + c;
        unsigned badr = (unsigned)(ct*128) + (((unsigned)(s2*64 + lq*16)) ^ (((unsigned)(ct&7)) << 4));
        bf16x8 bh = *(const bf16x8*)(HETH + badr);
        bf16x8 bl = *(const bf16x8*)(HETL + badr);
#pragma unroll
        for (int i = 0; i < 4; ++i) {
          int n = i*16 + l15;
          unsigned aadr = (unsigned)(n*128) + (((unsigned)(s2*64 + lq*16)) ^ (((unsigned)(n&7)) << 4));
          bf16x8 ah = *(const bf16x8*)(lds + sel*16384 + aadr);
          bf16x8 al = *(const bf16x8*)(lds + sel*16384 + 8192 + aadr);
          accS[sel][i] = __builtin_amdgcn_mfma_f32_16x16x32_bf16(ah, bh, accS[sel][i], 0,0,0);
          accS[sel][i] = __builtin_amdgcn_mfma_f32_16x16x32_bf16(ah, bl, accS[sel][i], 0,0,0);
          accS[sel][i] = __builtin_amdgcn_mfma_f32_16x16x32_bf16(al, bh, accS[sel][i], 0,0,0);
        }
      }
    }
    __syncthreads();   // AI & he_t reads done; safe to overwrite with IMG0/IMG1
#pragma unroll
    for (int sel = 0; sel < 2; ++sel) {
      float bv = sel ? b_oah[c] : b_iah[c];
      char* dH = sel ? IMG1H : IMG0H;
      char* dL = sel ? IMG1L : IMG0L;
#pragma unroll
      for (int i = 0; i < 4; ++i)
#pragma unroll
        for (int q = 0; q < 4; ++q) {
          int row = i*16 + lq*4 + q;
          float v = accS[sel][i][q] + bv;
          unsigned short hi = f2bf(v);
          unsigned short lo = f2bf(v - bf2f(hi));
          unsigned adr = row*256 + (((unsigned)(c*2)) ^ (((unsigned)(row&7)) << 4));
          *(unsigned short*)(dH + adr) = hi;
          *(unsigned short*)(dL + adr) = lo;
        }
    }
  }
  __syncthreads();

  // ---- P4: cat-GEMM [IN0|IN1|H] @ [w_ih|w_hh]^T + GRU epilogue ----
  f32x4 accRI[4][2], accNi[4], accNh[4];
#pragma unroll
  for (int i = 0; i < 4; ++i) {
    accRI[i][0] = (f32x4){0,0,0,0}; accRI[i][1] = (f32x4){0,0,0,0};
    accNi[i] = (f32x4){0,0,0,0};    accNh[i] = (f32x4){0,0,0,0};
  }
  const int nl = wid*16 + l15;

  auto cat_gemm = [&](const char* AH, const char* AL, int kh, bool toNh) {
    for (int s = 0; s < 4; ++s) {
      bf16x8 ah[4], al[4];
#pragma unroll
      for (int i = 0; i < 4; ++i) {
        int row = i*16 + l15;
        unsigned off = row*256 + (((unsigned)(s*64 + lq*16)) ^ (((unsigned)(row&7)) << 4));
        ah[i] = *(const bf16x8*)(AH + off);
        al[i] = *(const bf16x8*)(AL + off);
      }
#pragma unroll
      for (int g = 0; g < 2; ++g) {
        unsigned boff = (unsigned)((g*128 + nl)*768 + kh*256 + s*64 + lq*16);
        bf16x8 bh = *(const bf16x8*)(wsb + WS_WCATH + boff);
        bf16x8 bl = *(const bf16x8*)(wsb + WS_WCATL + boff);
#pragma unroll
        for (int i = 0; i < 4; ++i) {
          accRI[i][g] = __builtin_amdgcn_mfma_f32_16x16x32_bf16(ah[i], bh, accRI[i][g], 0,0,0);
          accRI[i][g] = __builtin_amdgcn_mfma_f32_16x16x32_bf16(ah[i], bl, accRI[i][g], 0,0,0);
          accRI[i][g] = __builtin_amdgcn_mfma_f32_16x16x32_bf16(al[i], bh, accRI[i][g], 0,0,0);
        }
      }
      {
        unsigned boff = (unsigned)((256 + nl)*768 + kh*256 + s*64 + lq*16);
        bf16x8 bh = *(const bf16x8*)(wsb + WS_WCATH + boff);
        bf16x8 bl = *(const bf16x8*)(wsb + WS_WCATL + boff);
        if (toNh) {
#pragma unroll
          for (int i = 0; i < 4; ++i) {
            accNh[i] = __builtin_amdgcn_mfma_f32_16x16x32_bf16(ah[i], bh, accNh[i], 0,0,0);
            accNh[i] = __builtin_amdgcn_mfma_f32_16x16x32_bf16(ah[i], bl, accNh[i], 0,0,0);
            accNh[i] = __builtin_amdgcn_mfma_f32_16x16x32_bf16(al[i], bh, accNh[i], 0,0,0);
          }
        } else {
#pragma unroll
          for (int i = 0; i < 4; ++i) {
            accNi[i] = __builtin_amdgcn_mfma_f32_16x16x32_bf16(ah[i], bh, accNi[i], 0,0,0);
            accNi[i] = __builtin_amdgcn_mfma_f32_16x16x32_bf16(ah[i], bl, accNi[i], 0,0,0);
            accNi[i] = __builtin_amdgcn_mfma_f32_16x16x32_bf16(al[i], bh, accNi[i], 0,0,0);
          }
        }
      }
    }
  };

  cat_gemm(IMG0H, IMG0L, 0, false);
  cat_gemm(IMG1H, IMG1L, 1, false);
  cat_gemm(HH,    HL,    2, true);
  __syncthreads();   // IMG1 reads done before H2 images overlay

  // ---- GRU pointwise epilogue -> H2f plain + H2 bf16 images ----
  {
    const int c = nl;
    float bir = b_ih[c], bii = b_ih[128+c], bin_ = b_ih[256+c];
    float bhr = b_hh[c], bhi = b_hh[128+c], bhn  = b_hh[256+c];
#pragma unroll
    for (int i = 0; i < 4; ++i) {
#pragma unroll
      for (int q = 0; q < 4; ++q) {
        int row = i*16 + lq*4 + q;
        if (row < 50) {
          float rg = sigm(accRI[i][0][q] + bir + bhr);
          float ig = sigm(accRI[i][1][q] + bii + bhi);
          float ng_ = tanhf(accNi[i][q] + bin_ + rg*(accNh[i][q] + bhn));
          unsigned byte = row*256 + (((unsigned)(c*2)) ^ (((unsigned)(row&7)) << 4));
          float h = bf2f(*(const unsigned short*)(HH + byte))
                  + bf2f(*(const unsigned short*)(HL + byte));
          float hn = ng_ + ig*(h - ng_);
          H2f[row*128 + c] = hn;
          unsigned short hi = f2bf(hn);
          unsigned short lo = f2bf(hn - bf2f(hi));
          *(unsigned short*)(H2H + byte) = hi;
          *(unsigned short*)(H2L + byte) = lo;
        }
      }
    }
  }
  __syncthreads();   // HH reads done -> small buffers may overlay

  if (tid < 64) ALI[tid] = (tid < LLn) ? alias_in[b*LLn + tid] : 0;
  __syncthreads();

  // ---- P5: attention readout ----
  int cnt = 0;
  for (int l = 0; l < LLn; ++l) cnt += (ALI[l] > 0) ? 1 : 0;
  int last = cnt - 1; if (last < 0) last = LLn - 1;
  const int a_last = ALI[last];

  const int c = tid & 127, h4 = tid >> 7;
  const float* W1T = (const float*)(wsb + WS_W1T);
  const float* WtT = (const float*)(wsb + WS_WTT);

  { // q1 partial over k-quarter (VALU, small)
    float q = 0.f;
    for (int k = h4*32; k < h4*32 + 32; k += 4) {
      float4 x = *(const float4*)&H2f[a_last*128 + k];
      q += x.x*W1T[(k<<7)+c] + x.y*W1T[((k+1)<<7)+c]
         + x.z*W1T[((k+2)<<7)+c] + x.w*W1T[((k+3)<<7)+c];
    }
    Q1P[h4*128 + c] = q;
  }
  __syncthreads();

  { // q2 via MFMA: rows l (gather alias), cols c, K=128
    const int cq = nl;
    f32x4 qa[4];
#pragma unroll
    for (int i = 0; i < 4; ++i) qa[i] = (f32x4){0,0,0,0};
    for (int s = 0; s < 4; ++s) {
      unsigned boff = (unsigned)(cq*256 + s*64 + lq*16);
      bf16x8 bh = *(const bf16x8*)(wsb + WS_W2H + boff);
      bf16x8 bl = *(const bf16x8*)(wsb + WS_W2L + boff);
#pragma unroll
      for (int i = 0; i < 4; ++i) {
        int ali = ALI[i*16 + l15];
        unsigned aadr = ali*256 + (((unsigned)(s*64 + lq*16)) ^ (((unsigned)(ali&7)) << 4));
        bf16x8 ah = *(const bf16x8*)(H2H + aadr);
        bf16x8 al = *(const bf16x8*)(H2L + aadr);
        qa[i] = __builtin_amdgcn_mfma_f32_16x16x32_bf16(ah, bh, qa[i], 0,0,0);
        qa[i] = __builtin_amdgcn_mfma_f32_16x16x32_bf16(ah, bl, qa[i], 0,0,0);
        qa[i] = __builtin_amdgcn_mfma_f32_16x16x32_bf16(al, bh, qa[i], 0,0,0);
      }
    }
    float q1c = Q1P[cq] + Q1P[128+cq] + Q1P[256+cq] + Q1P[384+cq] + b1[cq] + b2[cq];
#pragma unroll
    for (int i = 0; i < 4; ++i)
#pragma unroll
      for (int q = 0; q < 4; ++q) {
        int l = i*16 + lq*4 + q;
        if (l < 50) SIG[l*128 + cq] = sigm(q1c + qa[i][q]);
      }
  }
  __syncthreads();

  if (tid < 400) { // alpha = sig @ W3, 8 threads/row
    int l = tid >> 3, qd = tid & 7;
    float sum = 0.f;
    for (int cc = qd*16; cc < qd*16 + 16; cc += 4) {
      float4 x = *(const float4*)&SIG[l*128 + cc];
      sum += x.x*W3[cc] + x.y*W3[cc+1] + x.z*W3[cc+2] + x.w*W3[cc+3];
    }
    sum += __shfl_xor(sum, 1);
    sum += __shfl_xor(sum, 2);
    sum += __shfl_xor(sum, 4);
    if (qd == 0) ALP[l] = (ALI[l] > 0) ? sum : 0.f;
  }
  __syncthreads();

  { // a partial over l-quarter
    float acc = 0.f;
    int l0 = h4*13, l1 = l0 + 13; if (l1 > LLn) l1 = LLn;
    for (int l = l0; l < l1; ++l)
      acc += ALP[l] * H2f[ALI[l]*128 + c];
    AP[h4*128 + c] = acc;
  }
  __syncthreads();

  { // final r partial over k-quarter
    float r = 0.f;
    for (int k = h4*32; k < h4*32 + 32; ++k) {
      float av = AP[k] + AP[128+k] + AP[256+k] + AP[384+k];
      r += av * WtT[(k<<7) + c] + H2f[a_last*128 + k] * WtT[((128+k)<<7) + c];
    }
    RP[h4*128 + c] = r;
  }
  __syncthreads();

  if (tid < 128) {
    float r = bt_[c] + RP[c] + RP[128+c] + RP[256+c] + RP[384+c];
    int kh = c >> 6, kl = c & 63;
    unsigned int cb = (unsigned int)(kl*2) ^ (((unsigned int)(b & 7)) << 4);
    unsigned short hi = f2bf(r);
    unsigned short lo = f2bf(r - bf2f(hi));
    *(unsigned short*)(wsb + WS_AHI + kh*65536 + b*128 + cb) = hi;
    *(unsigned short*)(wsb + WS_ALO + kh*65536 + b*128 + cb) = lo;
  }
}

// ================= k2: scores GEMM (proven: per-kh E staging, stores at end) ======
__global__ __launch_bounds__(512) void k2_mfma(const float* __restrict__ emb,
                                               const char* __restrict__ wsb,
                                               float* __restrict__ out)
{
  extern __shared__ char ldsc[];
  char* AHI = ldsc;
  char* ALO = ldsc + 32768;
  char* EHI = ldsc + 65536;
  char* ELO = ldsc + 81920;

  const int tid  = threadIdx.x;
  const int lane = tid & 63;
  const int wid  = tid >> 6;
  const int wm   = wid >> 1;
  const int wn   = wid & 1;
  const int j0   = blockIdx.x * 128;
  const int l15  = lane & 15, lq = lane >> 4;

  f32x4 acc[2][4][4];
#pragma unroll
  for (int bi = 0; bi < 2; ++bi)
#pragma unroll
    for (int i = 0; i < 4; ++i)
#pragma unroll
      for (int j = 0; j < 4; ++j) acc[bi][i][j] = (f32x4){0.f, 0.f, 0.f, 0.f};

  for (int kh = 0; kh < 2; ++kh) {
    {
      int rbase = tid >> 4, c4 = tid & 15;
#pragma unroll
      for (int rr = 0; rr < 4; ++rr) {
        int row = rbase + rr*32;
        int j = j0 + row; if (j > OUTN - 1) j = OUTN - 1;
        float4 v = *(const float4*)&emb[(size_t)(1 + j)*HD + kh*64 + c4*4];
        ushort4 hi4, lo4;
        cvt4(v, hi4, lo4);
        unsigned int off = (unsigned int)(row*128) + (((unsigned int)(c4*8)) ^ (((unsigned int)(row&7)) << 4));
        *(ushort4*)(EHI + off) = hi4;
        *(ushort4*)(ELO + off) = lo4;
      }
    }
#pragma unroll
    for (int bi = 0; bi < 2; ++bi) {
      const char* srcH = wsb + WS_AHI + kh*65536 + bi*32768;
      const char* srcL = wsb + WS_ALO + kh*65536 + bi*32768;
#pragma unroll
      for (int r = 0; r < 4; ++r) {
        int off = (r*512 + tid) * 16;
        gl_lds16(srcH + off, AHI + off);
        gl_lds16(srcL + off, ALO + off);
      }
      __syncthreads();

#pragma unroll
      for (int s = 0; s < 2; ++s) {
        bf16x8 ah[4], al[4], bh[4], bl[4];
        const unsigned int cb = (unsigned int)(s*64 + (lq << 4));
#pragma unroll
        for (int i = 0; i < 4; ++i) {
          int row = wm*64 + i*16 + l15;
          unsigned int off = (unsigned int)(row*128) + (cb ^ (((unsigned int)(row&7)) << 4));
          ah[i] = *(const bf16x8*)(AHI + off);
          al[i] = *(const bf16x8*)(ALO + off);
        }
#pragma unroll
        for (int j = 0; j < 4; ++j) {
          int row = wn*64 + j*16 + l15;
          unsigned int off = (unsigned int)(row*128) + (cb ^ (((unsigned int)(row&7)) << 4));
          bh[j] = *(const bf16x8*)(EHI + off);
          bl[j] = *(const bf16x8*)(ELO + off);
        }
#pragma unroll
        for (int i = 0; i < 4; ++i)
#pragma unroll
          for (int j = 0; j < 4; ++j) {
            acc[bi][i][j] = __builtin_amdgcn_mfma_f32_16x16x32_bf16(ah[i], bh[j], acc[bi][i][j], 0, 0, 0);
            acc[bi][i][j] = __builtin_amdgcn_mfma_f32_16x16x32_bf16(ah[i], bl[j], acc[bi][i][j], 0, 0, 0);
            acc[bi][i][j] = __builtin_amdgcn_mfma_f32_16x16x32_bf16(al[i], bh[j], acc[bi][i][j], 0, 0, 0);
          }
      }
      __syncthreads();
    }
  }

#pragma unroll
  for (int bi = 0; bi < 2; ++bi)
#pragma unroll
    for (int i = 0; i < 4; ++i) {
#pragma unroll
      for (int j = 0; j < 4; ++j) {
        int jj = j0 + wn*64 + j*16 + l15;
        if (jj < OUTN) {
          size_t rowbase = (size_t)(bi*256 + wm*64 + i*16 + lq*4);
#pragma unroll
          for (int q = 0; q < 4; ++q)
            out[(rowbase + q)*OUTN + jj] = acc[bi][i][j][q];
        }
      }
    }
}

extern "C" void kernel_launch(void* const* d_in, const int* in_sizes, int n_in,
                              void* d_out, int out_size, void* d_ws, size_t ws_size,
                              hipStream_t stream)
{
  const int*   items  = (const int*)  d_in[0];
  const float* A      = (const float*)d_in[1];
  const int*   alias  = (const int*)  d_in[2];
  const float* emb    = (const float*)d_in[3];
  const float* w_ih   = (const float*)d_in[4];
  const float* w_hh   = (const float*)d_in[5];
  const float* b_ih   = (const float*)d_in[6];
  const float* b_hh   = (const float*)d_in[7];
  const float* b_iah  = (const float*)d_in[8];
  const float* b_oah  = (const float*)d_in[9];
  const float* W_ein  = (const float*)d_in[10];
  const float* b_ein  = (const float*)d_in[11];
  const float* W_eout = (const float*)d_in[12];
  const float* b_eout = (const float*)d_in[13];
  const float* W1     = (const float*)d_in[14];
  const float* b1     = (const float*)d_in[15];
  const float* W2     = (const float*)d_in[16];
  const float* b2     = (const float*)d_in[17];
  const float* W3     = (const float*)d_in[18];
  const float* Wt     = (const float*)d_in[19];
  const float* bt_    = (const float*)d_in[20];

  char*  wsb  = (char*)d_ws;
  float* outf = (float*)d_out;

  k0_prep<<<240, 256, 0, stream>>>(w_ih, w_hh, W_ein, W_eout, W1, W2, Wt, wsb);

  k1f<<<NB, 512, 131072, stream>>>(items, A, emb, alias, b_ein, b_eout, b_iah, b_oah,
                                   b_ih, b_hh, b1, b2, W3, bt_, wsb);

  k2_mfma<<<dim3(782, 1), 512, 98304, stream>>>(emb, (const char*)d_ws, outf);
}